// Round 2
// baseline (372.408 us; speedup 1.0000x reference)
//
#include <hip/hip_runtime.h>

typedef __attribute__((ext_vector_type(8))) short bf16x8;
typedef __attribute__((ext_vector_type(8))) unsigned short u16x8;
typedef __attribute__((ext_vector_type(4))) float f32x4;

__device__ __forceinline__ unsigned short f2bf(float f) {
    unsigned int u = __float_as_uint(f);
    u += 0x7fffu + ((u >> 16) & 1u);   // RNE
    return (unsigned short)(u >> 16);
}

// ---------------- Kernel 1: row-normalize fp32 -> bf16 ----------------
__global__ __launch_bounds__(256) void normalize_rows(
    const float* __restrict__ X, unsigned short* __restrict__ Y) {
    const int wave = threadIdx.x >> 6;
    const int lane = threadIdx.x & 63;
    const long row = (long)blockIdx.x * 4 + wave;

    const float4* xr = (const float4*)(X + row * 512);
    float4 a = xr[lane * 2];
    float4 b = xr[lane * 2 + 1];

    float s = a.x * a.x + a.y * a.y + a.z * a.z + a.w * a.w
            + b.x * b.x + b.y * b.y + b.z * b.z + b.w * b.w;
#pragma unroll
    for (int off = 32; off; off >>= 1) s += __shfl_xor(s, off, 64);

    const float inv = rsqrtf(s);   // norm ~22.6; eps never binds

    u16x8 o;
    o[0] = f2bf(a.x * inv); o[1] = f2bf(a.y * inv);
    o[2] = f2bf(a.z * inv); o[3] = f2bf(a.w * inv);
    o[4] = f2bf(b.x * inv); o[5] = f2bf(b.y * inv);
    o[6] = f2bf(b.z * inv); o[7] = f2bf(b.w * inv);
    ((u16x8*)(Y + row * 512))[lane] = o;
}

// ---------------- Kernel 2: C = 1 - Y*Y^T, 256x256 tri tiles ----------------
// 8 waves (2x4), each wave 128x64 = 8x4 frags of 16x16x32. BK=64.
// LDS: double-buffered A,B tiles [256][64] bf16 (32KB each) = 128KB.
// T2 swizzle: 16B chunk ci of row r holds global chunk ci^(r&7)
//   (linear GLDS dest + pre-swizzled global SOURCE + swizzled ds_read).
// K-loop: 4 quadrant-phases per K-step; prefetch of kt+1 issued one
// quarter-tile per phase (issue-early/drain-late); setprio around MFMA.
#define GLDS16(g, l)                                                         \
    __builtin_amdgcn_global_load_lds(                                        \
        (const __attribute__((address_space(1))) void*)(g),                  \
        (__attribute__((address_space(3))) void*)(l), 16, 0, 0)

// swizzled fragment read: row r (incl. frow), 16B-chunk c (0..7)
#define RD(base, r, c) \
    (*(const bf16x8*)((base) + (r) * 64 + ((((c) ^ ((r) & 7))) << 3)))

__global__ __launch_bounds__(512, 2) void cosdist_gemm_sym(
    const unsigned short* __restrict__ Y, float* __restrict__ out) {
    constexpr int N = 8192, K = 512, BM = 256;
    constexpr int NT = N / BM;          // 32 tile rows
    constexpr int A2 = 2 * NT + 1;      // 65
    constexpr int TILE = BM * 64;       // 16384 shorts = 32KB

    __shared__ __align__(16) short As[2 * TILE];
    __shared__ __align__(16) short Bs[2 * TILE];

    // ---- XCD-aware chunked remap (528 % 8 == 0 -> bijective) ----
    constexpr int NWG = NT * (NT + 1) / 2;   // 528
    constexpr int CPX = NWG / 8;             // 66
    const int hw = blockIdx.x;
    const int p = (hw & 7) * CPX + (hw >> 3);

    // ---- triangular decode: p -> (bi, bj), bi <= bj ----
    int bi = (int)floorf(((float)A2 - sqrtf((float)(A2 * A2) - 8.0f * (float)p)) * 0.5f);
    while ((bi + 1) * (A2 - (bi + 1)) / 2 <= p) ++bi;
    while (bi * (A2 - bi) / 2 > p) --bi;
    const int bj = bi + (p - bi * (A2 - bi) / 2);
    const int bm = bi * BM, bn = bj * BM;

    const int tid  = threadIdx.x;
    const int lane = tid & 63;
    const int wave = tid >> 6;      // 0..7
    const int wr = wave >> 2;       // 0..1 : row half (128 rows)
    const int wc = wave & 3;        // 0..3 : col quarter (64 cols)
    const int frow = lane & 15;
    const int fch  = lane >> 4;     // 0..3

    // ---- staging map: per matrix 2048 x 16B chunks / K-step ----
    // phase j stages chunk q = j*512 + tid: local row q>>3, chunk-in-row q&7.
    // LDS dest is LINEAR (q*16B); global source chunk is (q&7) ^ (row&7).
    const int srow = tid >> 3;                 // row within 64-row quarter
    const int sgc  = (tid & 7) ^ (srow & 7);   // pre-swizzled source chunk
    const unsigned short* Abase = Y + (size_t)(bm + srow) * K + (sgc << 3);
    const unsigned short* Bbase = Y + (size_t)(bn + srow) * K + (sgc << 3);
    const size_t QSTEP = (size_t)64 * K;       // next 64-row quarter

    f32x4 acc[8][4] = {};

    // ---- prologue: stage K-step 0 into buffer 0 ----
#pragma unroll
    for (int j = 0; j < 4; ++j) {
        GLDS16(Abase + (size_t)j * QSTEP, As + j * 4096 + tid * 8);
        GLDS16(Bbase + (size_t)j * QSTEP, Bs + j * 4096 + tid * 8);
    }
    __syncthreads();

    for (int kt = 0; kt < 8; ++kt) {
        const short* Ac = As + (kt & 1) * TILE;
        const short* Bc = Bs + (kt & 1) * TILE;
        short* An = As + ((kt + 1) & 1) * TILE;
        short* Bn = Bs + ((kt + 1) & 1) * TILE;
        const int kn = (kt + 1) << 6;
        const bool pf = (kt < 7);

        bf16x8 af[4][2], bfv[2][2];

        // ===== phase 0: rows 0-63 (mh=0), cols 0-31 (nh=0) =====
        if (pf) {
            GLDS16(Abase + kn, An + tid * 8);
            GLDS16(Bbase + kn, Bn + tid * 8);
        }
#pragma unroll
        for (int m = 0; m < 4; ++m) {
            const int r = wr * 128 + m * 16 + frow;
            af[m][0] = RD(Ac, r, fch);
            af[m][1] = RD(Ac, r, 4 + fch);
        }
#pragma unroll
        for (int n = 0; n < 2; ++n) {
            const int r = wc * 64 + n * 16 + frow;
            bfv[n][0] = RD(Bc, r, fch);
            bfv[n][1] = RD(Bc, r, 4 + fch);
        }
        __builtin_amdgcn_s_setprio(1);
#pragma unroll
        for (int m = 0; m < 4; ++m)
#pragma unroll
            for (int n = 0; n < 2; ++n)
#pragma unroll
                for (int kk = 0; kk < 2; ++kk)
                    acc[m][n] = __builtin_amdgcn_mfma_f32_16x16x32_bf16(
                        af[m][kk], bfv[n][kk], acc[m][n], 0, 0, 0);
        __builtin_amdgcn_s_setprio(0);
        __builtin_amdgcn_s_barrier();

        // ===== phase 1: same rows, cols 32-63 (nh=1) — reuse af =====
        if (pf) {
            GLDS16(Abase + kn + QSTEP, An + 4096 + tid * 8);
            GLDS16(Bbase + kn + QSTEP, Bn + 4096 + tid * 8);
        }
#pragma unroll
        for (int n = 0; n < 2; ++n) {
            const int r = wc * 64 + (n + 2) * 16 + frow;
            bfv[n][0] = RD(Bc, r, fch);
            bfv[n][1] = RD(Bc, r, 4 + fch);
        }
        __builtin_amdgcn_s_setprio(1);
#pragma unroll
        for (int m = 0; m < 4; ++m)
#pragma unroll
            for (int n = 0; n < 2; ++n)
#pragma unroll
                for (int kk = 0; kk < 2; ++kk)
                    acc[m][n + 2] = __builtin_amdgcn_mfma_f32_16x16x32_bf16(
                        af[m][kk], bfv[n][kk], acc[m][n + 2], 0, 0, 0);
        __builtin_amdgcn_s_setprio(0);
        __builtin_amdgcn_s_barrier();

        // ===== phase 2: rows 64-127 (mh=1), cols 32-63 — reuse bfv =====
        if (pf) {
            GLDS16(Abase + kn + 2 * QSTEP, An + 2 * 4096 + tid * 8);
            GLDS16(Bbase + kn + 2 * QSTEP, Bn + 2 * 4096 + tid * 8);
        }
#pragma unroll
        for (int m = 0; m < 4; ++m) {
            const int r = wr * 128 + (m + 4) * 16 + frow;
            af[m][0] = RD(Ac, r, fch);
            af[m][1] = RD(Ac, r, 4 + fch);
        }
        __builtin_amdgcn_s_setprio(1);
#pragma unroll
        for (int m = 0; m < 4; ++m)
#pragma unroll
            for (int n = 0; n < 2; ++n)
#pragma unroll
                for (int kk = 0; kk < 2; ++kk)
                    acc[m + 4][n + 2] = __builtin_amdgcn_mfma_f32_16x16x32_bf16(
                        af[m][kk], bfv[n][kk], acc[m + 4][n + 2], 0, 0, 0);
        __builtin_amdgcn_s_setprio(0);
        __builtin_amdgcn_s_barrier();

        // ===== phase 3: rows 64-127, cols 0-31 — reuse af =====
        if (pf) {
            GLDS16(Abase + kn + 3 * QSTEP, An + 3 * 4096 + tid * 8);
            GLDS16(Bbase + kn + 3 * QSTEP, Bn + 3 * 4096 + tid * 8);
        }
#pragma unroll
        for (int n = 0; n < 2; ++n) {
            const int r = wc * 64 + n * 16 + frow;
            bfv[n][0] = RD(Bc, r, fch);
            bfv[n][1] = RD(Bc, r, 4 + fch);
        }
        __builtin_amdgcn_s_setprio(1);
#pragma unroll
        for (int m = 0; m < 4; ++m)
#pragma unroll
            for (int n = 0; n < 2; ++n)
#pragma unroll
                for (int kk = 0; kk < 2; ++kk)
                    acc[m + 4][n] = __builtin_amdgcn_mfma_f32_16x16x32_bf16(
                        af[m][kk], bfv[n][kk], acc[m + 4][n], 0, 0, 0);
        __builtin_amdgcn_s_setprio(0);
        __syncthreads();   // drains vmcnt: next buffer fully staged
    }

    // ---- epilogue: C/D map col=lane&15, row=(lane>>4)*4+r ----
    const int rbase = bm + wr * 128 + (fch << 2);
    const int cbase = bn + wc * 64 + frow;
    const bool offdiag = (bm != bn);

#pragma unroll
    for (int m = 0; m < 8; ++m)
#pragma unroll
        for (int n = 0; n < 4; ++n) {
            f32x4 v;
#pragma unroll
            for (int r = 0; r < 4; ++r) v[r] = 1.0f - acc[m][n][r];
            const int row = rbase + m * 16;   // rows row..row+3
            const int col = cbase + n * 16;

            // mirror tile (bj,bi): 16B store; covers diagonal tile exactly once
            *(f32x4*)&out[(size_t)col * N + row] = v;

            if (offdiag) {
#pragma unroll
                for (int r = 0; r < 4; ++r)
                    out[(size_t)(row + r) * N + col] = v[r];
            }
        }
}

extern "C" void kernel_launch(void* const* d_in, const int* in_sizes, int n_in,
                              void* d_out, int out_size, void* d_ws, size_t ws_size,
                              hipStream_t stream) {
    const float* X = (const float*)d_in[0];          // fp32 [N,512]
    float* out = (float*)d_out;                      // fp32 [N,N]
    unsigned short* Y = (unsigned short*)d_ws;       // bf16 [N,512] scratch

    const int D = 512;
    const int N = in_sizes[0] / D;   // 8192

    normalize_rows<<<N / 4, 256, 0, stream>>>(X, Y);

    const int nt = N / 256;                          // 32
    const int ntiles = nt * (nt + 1) / 2;            // 528 triangular tiles
    cosdist_gemm_sym<<<ntiles, 512, 0, stream>>>(Y, out);
}

// Round 5
// 369.045 us; speedup vs baseline: 1.0091x; 1.0091x over previous
//
#include <hip/hip_runtime.h>

typedef __attribute__((ext_vector_type(8))) short bf16x8;
typedef __attribute__((ext_vector_type(8))) unsigned short u16x8;
typedef __attribute__((ext_vector_type(4))) float f32x4;

__device__ __forceinline__ unsigned short f2bf(float f) {
    unsigned int u = __float_as_uint(f);
    u += 0x7fffu + ((u >> 16) & 1u);   // RNE
    return (unsigned short)(u >> 16);
}

// ---------------- Kernel 1: row-normalize fp32 -> bf16 ----------------
__global__ __launch_bounds__(256) void normalize_rows(
    const float* __restrict__ X, unsigned short* __restrict__ Y) {
    const int wave = threadIdx.x >> 6;
    const int lane = threadIdx.x & 63;
    const long row = (long)blockIdx.x * 4 + wave;

    const float4* xr = (const float4*)(X + row * 512);
    float4 a = xr[lane * 2];
    float4 b = xr[lane * 2 + 1];

    float s = a.x * a.x + a.y * a.y + a.z * a.z + a.w * a.w
            + b.x * b.x + b.y * b.y + b.z * b.z + b.w * b.w;
#pragma unroll
    for (int off = 32; off; off >>= 1) s += __shfl_xor(s, off, 64);

    const float inv = rsqrtf(s);   // norm ~22.6; eps never binds

    u16x8 o;
    o[0] = f2bf(a.x * inv); o[1] = f2bf(a.y * inv);
    o[2] = f2bf(a.z * inv); o[3] = f2bf(a.w * inv);
    o[4] = f2bf(b.x * inv); o[5] = f2bf(b.y * inv);
    o[6] = f2bf(b.z * inv); o[7] = f2bf(b.w * inv);
    ((u16x8*)(Y + row * 512))[lane] = o;
}

// ---------------- Kernel 2: C = 1 - Y*Y^T, 256x256 tri tiles ----------------
// 8 waves (2x4), wave tile 128x64, BK=64, double-buffered 128KB LDS, T2 swizzle.
// T4 counted-vmcnt pipeline: K-tile t+1 staged one slab per phase of t, in
// NEED order (A q0/q2, A q1/q3, B even-strips, B odd-strips); gates vmcnt(2)
// before ph0 and ph1 only -- loads never drain to 0 in the main loop.
#define GLDS16(g, l)                                                         \
    __builtin_amdgcn_global_load_lds(                                        \
        (const __attribute__((address_space(1))) void*)(g),                  \
        (__attribute__((address_space(3))) void*)(l), 16, 0, 0)

// swizzled fragment read: row r (0..255), 16B-chunk c (0..7); row stride 128B
#define RD(base, r, c) \
    (*(const bf16x8*)((base) + (r) * 64 + ((((c) ^ ((r) & 7))) << 3)))

__global__ __launch_bounds__(512, 2) void cosdist_gemm_sym(
    const unsigned short* __restrict__ Y, float* __restrict__ out) {
    constexpr int N = 8192, K = 512, BM = 256;
    constexpr int NT = N / BM;          // 32 tile rows
    constexpr int A2 = 2 * NT + 1;      // 65
    constexpr int TILE = BM * 64;       // 16384 shorts = 32KB

    __shared__ __align__(16) short As[2 * TILE];
    __shared__ __align__(16) short Bs[2 * TILE];

    // ---- XCD-aware chunked remap (528 % 8 == 0 -> bijective) ----
    constexpr int NWG = NT * (NT + 1) / 2;   // 528
    constexpr int CPX = NWG / 8;             // 66
    const int hw = blockIdx.x;
    const int p = (hw & 7) * CPX + (hw >> 3);

    // ---- triangular decode: p -> (bi, bj), bi <= bj ----
    int bi = (int)floorf(((float)A2 - sqrtf((float)(A2 * A2) - 8.0f * (float)p)) * 0.5f);
    while ((bi + 1) * (A2 - (bi + 1)) / 2 <= p) ++bi;
    while (bi * (A2 - bi) / 2 > p) --bi;
    const int bj = bi + (p - bi * (A2 - bi) / 2);
    const int bm = bi * BM, bn = bj * BM;

    const int tid  = threadIdx.x;
    const int lane = tid & 63;
    const int wave = tid >> 6;      // 0..7
    const int wr = wave >> 2;       // 0..1 : row half (128 rows)
    const int wc = wave & 3;        // 0..3 : col quarter (64 cols)
    const int frow = lane & 15;
    const int fch  = lane >> 4;     // 0..3

    // ---- staging thread map ----
    // i6 = row-in-slab (0..63), chunk j = tid&7; source chunk pre-swizzled.
    const int i6  = tid >> 3;
    const int sgc = (tid & 7) ^ (i6 & 7);
    // A quarter q: row = q*64 + i6 ; LDS dest = buf + q*4096 + tid*8 (linear)
    const unsigned short* Asrc = Y + (size_t)(bm + i6) * K + (sgc << 3);
    // B strip slab (h,nh): row = h*128 + (i6>>5)*64 + nh*32 + (i6&31)
    const int rB = ((i6 >> 5) << 6) + (i6 & 31);
    const unsigned short* Bsrc = Y + (size_t)(bn + rB) * K + (sgc << 3);
    const int boff = ((i6 >> 5) << 12) + ((i6 & 31) << 6) + ((tid & 7) << 3);

    f32x4 acc[8][4] = {};

    // ---- prologue: stage K-tile 0 into buffer 0, NEED order ----
    GLDS16(Asrc,                   As + tid * 8);             // A q0
    GLDS16(Asrc + 2 * 32768,       As + 2 * 4096 + tid * 8);  // A q2
    GLDS16(Asrc + 1 * 32768,       As + 1 * 4096 + tid * 8);  // A q1
    GLDS16(Asrc + 3 * 32768,       As + 3 * 4096 + tid * 8);  // A q3
    GLDS16(Bsrc,                   Bs + boff);                // B even h0
    GLDS16(Bsrc + 65536,           Bs + 8192 + boff);         // B even h1
    GLDS16(Bsrc + 16384,           Bs + 2048 + boff);         // B odd  h0
    GLDS16(Bsrc + 81920,           Bs + 10240 + boff);        // B odd  h1

    for (int kt = 0; kt < 8; ++kt) {
        const short* Ac = As + (kt & 1) * TILE;
        const short* Bc = Bs + (kt & 1) * TILE;
        short* An = As + ((kt + 1) & 1) * TILE;
        short* Bn = Bs + ((kt + 1) & 1) * TILE;
        const int kn = (kt + 1) << 6;   // shorts
        const bool pf = (kt < 7);

        bf16x8 af[4][2], bfv[2][2];

        // ===== phase 0: (mh0, nh0) =====
        asm volatile("s_waitcnt vmcnt(2)" ::: "memory");
        __builtin_amdgcn_s_barrier();
        if (pf) {   // stage A q0, q2 of kt+1
            GLDS16(Asrc + kn,             An + tid * 8);
            GLDS16(Asrc + 2 * 32768 + kn, An + 2 * 4096 + tid * 8);
        }
#pragma unroll
        for (int m = 0; m < 4; ++m) {
            const int r = wr * 128 + m * 16 + frow;
            af[m][0] = RD(Ac, r, fch);
            af[m][1] = RD(Ac, r, 4 + fch);
        }
#pragma unroll
        for (int n = 0; n < 2; ++n) {
            const int r = wc * 64 + n * 16 + frow;
            bfv[n][0] = RD(Bc, r, fch);
            bfv[n][1] = RD(Bc, r, 4 + fch);
        }
        __builtin_amdgcn_s_setprio(1);
#pragma unroll
        for (int m = 0; m < 4; ++m)
#pragma unroll
            for (int n = 0; n < 2; ++n)
#pragma unroll
                for (int kk = 0; kk < 2; ++kk)
                    acc[m][n] = __builtin_amdgcn_mfma_f32_16x16x32_bf16(
                        af[m][kk], bfv[n][kk], acc[m][n], 0, 0, 0);
        __builtin_amdgcn_s_setprio(0);

        // ===== phase 1: (mh0, nh1) — reuse af =====
        if (pf) asm volatile("s_waitcnt vmcnt(2)" ::: "memory");
        else    asm volatile("s_waitcnt vmcnt(0)" ::: "memory");
        __builtin_amdgcn_s_barrier();
        if (pf) {   // stage A q1, q3 of kt+1
            GLDS16(Asrc + 1 * 32768 + kn, An + 1 * 4096 + tid * 8);
            GLDS16(Asrc + 3 * 32768 + kn, An + 3 * 4096 + tid * 8);
        }
#pragma unroll
        for (int n = 0; n < 2; ++n) {
            const int r = wc * 64 + 32 + n * 16 + frow;
            bfv[n][0] = RD(Bc, r, fch);
            bfv[n][1] = RD(Bc, r, 4 + fch);
        }
        __builtin_amdgcn_s_setprio(1);
#pragma unroll
        for (int m = 0; m < 4; ++m)
#pragma unroll
            for (int n = 0; n < 2; ++n)
#pragma unroll
                for (int kk = 0; kk < 2; ++kk)
                    acc[m][n + 2] = __builtin_amdgcn_mfma_f32_16x16x32_bf16(
                        af[m][kk], bfv[n][kk], acc[m][n + 2], 0, 0, 0);
        __builtin_amdgcn_s_setprio(0);

        // ===== phase 2: (mh1, nh1) — reuse bfv =====
        __builtin_amdgcn_s_barrier();
        if (pf) {   // stage B even strips of kt+1
            GLDS16(Bsrc + kn,         Bn + boff);
            GLDS16(Bsrc + 65536 + kn, Bn + 8192 + boff);
        }
#pragma unroll
        for (int m = 0; m < 4; ++m) {
            const int r = wr * 128 + 64 + m * 16 + frow;
            af[m][0] = RD(Ac, r, fch);
            af[m][1] = RD(Ac, r, 4 + fch);
        }
        __builtin_amdgcn_s_setprio(1);
#pragma unroll
        for (int m = 0; m < 4; ++m)
#pragma unroll
            for (int n = 0; n < 2; ++n)
#pragma unroll
                for (int kk = 0; kk < 2; ++kk)
                    acc[m + 4][n + 2] = __builtin_amdgcn_mfma_f32_16x16x32_bf16(
                        af[m][kk], bfv[n][kk], acc[m + 4][n + 2], 0, 0, 0);
        __builtin_amdgcn_s_setprio(0);

        // ===== phase 3: (mh1, nh0) — reuse af =====
        __builtin_amdgcn_s_barrier();
        if (pf) {   // stage B odd strips of kt+1
            GLDS16(Bsrc + 16384 + kn, Bn + 2048 + boff);
            GLDS16(Bsrc + 81920 + kn, Bn + 10240 + boff);
        }
#pragma unroll
        for (int n = 0; n < 2; ++n) {
            const int r = wc * 64 + n * 16 + frow;
            bfv[n][0] = RD(Bc, r, fch);
            bfv[n][1] = RD(Bc, r, 4 + fch);
        }
        __builtin_amdgcn_s_setprio(1);
#pragma unroll
        for (int m = 0; m < 4; ++m)
#pragma unroll
            for (int n = 0; n < 2; ++n)
#pragma unroll
                for (int kk = 0; kk < 2; ++kk)
                    acc[m + 4][n] = __builtin_amdgcn_mfma_f32_16x16x32_bf16(
                        af[m][kk], bfv[n][kk], acc[m + 4][n], 0, 0, 0);
        __builtin_amdgcn_s_setprio(0);
    }

    // ---- epilogue: C/D map col=lane&15, row=(lane>>4)*4+r ----
    const int rbase = bm + wr * 128 + (fch << 2);
    const int cbase = bn + wc * 64 + frow;
    const bool offdiag = (bm != bn);

#pragma unroll
    for (int m = 0; m < 8; ++m)
#pragma unroll
        for (int n = 0; n < 4; ++n) {
            f32x4 v;
#pragma unroll
            for (int r = 0; r < 4; ++r) v[r] = 1.0f - acc[m][n][r];
            const int row = rbase + m * 16;   // rows row..row+3
            const int col = cbase + n * 16;

            // mirror tile (bj,bi): 16B store; covers diagonal tile exactly once
            *(f32x4*)&out[(size_t)col * N + row] = v;

            if (offdiag) {
#pragma unroll
                for (int r = 0; r < 4; ++r)
                    out[(size_t)(row + r) * N + col] = v[r];
            }
        }
}

extern "C" void kernel_launch(void* const* d_in, const int* in_sizes, int n_in,
                              void* d_out, int out_size, void* d_ws, size_t ws_size,
                              hipStream_t stream) {
    const float* X = (const float*)d_in[0];          // fp32 [N,512]
    float* out = (float*)d_out;                      // fp32 [N,N]
    unsigned short* Y = (unsigned short*)d_ws;       // bf16 [N,512] scratch

    const int D = 512;
    const int N = in_sizes[0] / D;   // 8192

    normalize_rows<<<N / 4, 256, 0, stream>>>(X, Y);

    const int nt = N / 256;                          // 32
    const int ntiles = nt * (nt + 1) / 2;            // 528 triangular tiles
    cosdist_gemm_sym<<<ntiles, 512, 0, stream>>>(Y, out);
}

// Round 6
// 345.511 us; speedup vs baseline: 1.0778x; 1.0681x over previous
//
#include <hip/hip_runtime.h>

typedef __attribute__((ext_vector_type(8))) short bf16x8;
typedef __attribute__((ext_vector_type(8))) unsigned short u16x8;
typedef __attribute__((ext_vector_type(4))) float f32x4;

__device__ __forceinline__ unsigned short f2bf(float f) {
    unsigned int u = __float_as_uint(f);
    u += 0x7fffu + ((u >> 16) & 1u);   // RNE
    return (unsigned short)(u >> 16);
}

// ---------------- Kernel 1: row-normalize fp32 -> bf16 ----------------
__global__ __launch_bounds__(256) void normalize_rows(
    const float* __restrict__ X, unsigned short* __restrict__ Y) {
    const int wave = threadIdx.x >> 6;
    const int lane = threadIdx.x & 63;
    const long row = (long)blockIdx.x * 4 + wave;

    const float4* xr = (const float4*)(X + row * 512);
    float4 a = xr[lane * 2];
    float4 b = xr[lane * 2 + 1];

    float s = a.x * a.x + a.y * a.y + a.z * a.z + a.w * a.w
            + b.x * b.x + b.y * b.y + b.z * b.z + b.w * b.w;
#pragma unroll
    for (int off = 32; off; off >>= 1) s += __shfl_xor(s, off, 64);

    const float inv = rsqrtf(s);   // norm ~22.6; eps never binds

    u16x8 o;
    o[0] = f2bf(a.x * inv); o[1] = f2bf(a.y * inv);
    o[2] = f2bf(a.z * inv); o[3] = f2bf(a.w * inv);
    o[4] = f2bf(b.x * inv); o[5] = f2bf(b.y * inv);
    o[6] = f2bf(b.z * inv); o[7] = f2bf(b.w * inv);
    ((u16x8*)(Y + row * 512))[lane] = o;
}

// ---------------- Kernel 2: C = 1 - Y*Y^T, 128x128 tri tiles, BK=64 ----------------
// R1 base structure (proven best): 4 waves 2x2, wave tile 64x64 = 4x4 of
// 16x16x32, 3 blocks/CU so TLP covers the staging drain. Changes vs R1:
//   - BK=64: 8 K-steps instead of 16 -> half the barrier events.
//   - T2 r&7 XOR swizzle on the [128][64]-short tiles (128B rows would be a
//     16-way read conflict unswizzled; R1's 64B rows were 8-way). Linear GLDS
//     dest + pre-swizzled global source + swizzled ds_read (both-sides rule).
#define GLDS16(g, l)                                                         \
    __builtin_amdgcn_global_load_lds(                                        \
        (const __attribute__((address_space(1))) void*)(g),                  \
        (__attribute__((address_space(3))) void*)(l), 16, 0, 0)

// swizzled fragment read: row r (0..127), 16B-chunk g (0..7); row = 64 shorts
#define RD(base, r, g) \
    (*(const bf16x8*)((base) + (r) * 64 + ((((g) ^ ((r) & 7))) << 3)))

__global__ __launch_bounds__(256) void cosdist_gemm_sym(
    const unsigned short* __restrict__ Y, float* __restrict__ out) {
    constexpr int N = 8192, K = 512, BM = 128, BK = 64;
    constexpr int NTI = N / BM;          // 64 tile rows
    constexpr int A2 = 2 * NTI + 1;      // 129

    __shared__ __align__(16) short As[BM * BK];
    __shared__ __align__(16) short Bs[BM * BK];

    // ---- triangular decode: p -> (bi, bj), bi <= bj ----
    const int p = blockIdx.x;
    int bi = (int)floorf(((float)A2 - sqrtf((float)(A2 * A2) - 8.0f * (float)p)) * 0.5f);
    while ((bi + 1) * (A2 - (bi + 1)) / 2 <= p) ++bi;
    while (bi * (A2 - bi) / 2 > p) --bi;
    const int bj = bi + (p - bi * (A2 - bi) / 2);
    const int bm = bi * BM;
    const int bn = bj * BM;

    const int tid  = threadIdx.x;
    const int lane = tid & 63;
    const int wave = tid >> 6;
    const int wr = wave >> 1, wc = wave & 1;
    const int frow = lane & 15;
    const int fch  = lane >> 4;          // 0..3

    // ---- staging map: batch b covers rows b*32..b*32+31 of the tile ----
    // thread -> row srow = tid>>3, LDS chunk tid&7 (dest linear: b*2048+tid*8),
    // global source chunk pre-swizzled: (tid&7) ^ (srow&7).
    const int srow = tid >> 3;                  // 0..31
    const int sgc  = (tid & 7) ^ (srow & 7);
    const unsigned short* Asrc = Y + (size_t)(bm + srow) * K + (sgc << 3);
    const unsigned short* Bsrc = Y + (size_t)(bn + srow) * K + (sgc << 3);
    const size_t RSTEP = (size_t)32 * K;        // 32 rows of global stride

    f32x4 acc[4][4] = {};

    for (int k0 = 0; k0 < K; k0 += BK) {
#pragma unroll
        for (int b = 0; b < 4; ++b) {
            GLDS16(Asrc + b * RSTEP + k0, As + b * 2048 + tid * 8);
            GLDS16(Bsrc + b * RSTEP + k0, Bs + b * 2048 + tid * 8);
        }
        __syncthreads();   // drains vmcnt before s_barrier

        bf16x8 af[4][2], bfv[4][2];
#pragma unroll
        for (int t = 0; t < 4; ++t) {
            const int ra = wr * 64 + t * 16 + frow;
            const int rb = wc * 64 + t * 16 + frow;
            af[t][0]  = RD(As, ra, fch);
            af[t][1]  = RD(As, ra, 4 + fch);
            bfv[t][0] = RD(Bs, rb, fch);
            bfv[t][1] = RD(Bs, rb, 4 + fch);
        }
#pragma unroll
        for (int mt = 0; mt < 4; ++mt)
#pragma unroll
            for (int nt = 0; nt < 4; ++nt)
#pragma unroll
                for (int kk = 0; kk < 2; ++kk)
                    acc[mt][nt] = __builtin_amdgcn_mfma_f32_16x16x32_bf16(
                        af[mt][kk], bfv[nt][kk], acc[mt][nt], 0, 0, 0);
        __syncthreads();
    }

    // ---- epilogue (identical to R1): C/D map col=lane&15, row=(lane>>4)*4+r
    const int crow0 = wr * 64 + (fch << 2);
    const int ccol0 = wc * 64 + frow;
    const bool offdiag = (bm != bn);

#pragma unroll
    for (int mt = 0; mt < 4; ++mt)
#pragma unroll
        for (int nt = 0; nt < 4; ++nt) {
            f32x4 v;
#pragma unroll
            for (int r = 0; r < 4; ++r) v[r] = 1.0f - acc[mt][nt][r];
            const int row = bm + crow0 + mt * 16;   // rows row..row+3
            const int col = bn + ccol0 + nt * 16;

            // mirror tile (bj,bi): 16B store; covers diagonal tile exactly once
            *(f32x4*)&out[(size_t)col * N + row] = v;

            if (offdiag) {
#pragma unroll
                for (int r = 0; r < 4; ++r)
                    out[(size_t)(row + r) * N + col] = v[r];
            }
        }
}

extern "C" void kernel_launch(void* const* d_in, const int* in_sizes, int n_in,
                              void* d_out, int out_size, void* d_ws, size_t ws_size,
                              hipStream_t stream) {
    const float* X = (const float*)d_in[0];          // fp32 [N,512]
    float* out = (float*)d_out;                      // fp32 [N,N]
    unsigned short* Y = (unsigned short*)d_ws;       // bf16 [N,512] scratch

    const int D = 512;
    const int N = in_sizes[0] / D;   // 8192

    normalize_rows<<<N / 4, 256, 0, stream>>>(X, Y);

    const int nt = N / 128;                          // 64
    const int ntiles = nt * (nt + 1) / 2;            // 2080 triangular tiles
    cosdist_gemm_sym<<<ntiles, 256, 0, stream>>>(Y, out);
}